// Round 3
// baseline (327.237 us; speedup 1.0000x reference)
//
#include <hip/hip_runtime.h>

#define N_NODES 100000
#define N_EDGES 1600000
#define IN_CH   128
#define HEADS   4
#define OUT_CH  32
#define HID     128   // HEADS*OUT_CH
#define NEG_SLOPE 0.2f

#define BNODES  512                       // nodes per bucket (pow2)
#define NBUCK   ((N_NODES + BNODES - 1) / BNODES)   // 196
#define NBLK    256                       // scatter blocks
#define EPB     (N_EDGES / NBLK)          // 6250 edges per block (exact)
#define BSLOT   9216                      // padded slots per bucket (mean 8192, +11 sigma)

typedef unsigned int  uint;
typedef unsigned short ushort;

// bf16 round-to-nearest-even pack
__device__ __forceinline__ ushort f2bf(float f) {
    uint u = __float_as_uint(f);
    return (ushort)((u + 0x7FFFu + ((u >> 16) & 1u)) >> 16);
}

// ---------------- K1: h = x @ W (fp32, bf16 store) + fused attention scores ----------------
// BM=128, BK=32, 256 threads. Per thread: 8 nodes x 8 channels (4 lo + 4 hi).
//   channel quad q = tid&15: ch_lo = 4q, ch_hi = 64+4q  -> wsld reads are 256B
//   lane-contiguous (2-way max, free).
//   node group v8 = (tid>>4)*8.
// x tile staged TRANSPOSED [k][node] in a pad-free 16KB buffer with bijective XOR
// swizzle  W' = W ^ ((((W>>9)&7) ^ ((W>>5)&3)) << 2)  -- makes both the scalar
// transpose stores and the b128 fragment reads 2-way max (was 4-way / 7.6M conflicts).
// Next K-tile is prefetched into registers during the FMA loop.
#define BM 128
#define BK 32
__global__ __launch_bounds__(256) void k_gemm(const float* __restrict__ x,
                                              const float* __restrict__ w,
                                              const float* __restrict__ att,
                                              ushort* __restrict__ h,
                                              float* __restrict__ s_src,
                                              float* __restrict__ s_dst,
                                              int* __restrict__ bucket_cnt) {
    __shared__ float xsw[BK * BM];            // 16 KB, swizzled [k][node]
    __shared__ float wsld[BK][HID + 4];       // 16.9 KB

    const int tid = threadIdx.x;
    const int nodeBase = blockIdx.x * BM;
    const int q   = tid & 15;                 // channel quad id
    const int v8  = (tid >> 4) * 8;           // node sub-block base (0..120)
    const int cLo = q * 4;
    const int cHi = 64 + q * 4;

    // zero bucket reservation counters (k_scatter runs after us, stream-ordered)
    if (blockIdx.x == 0 && tid < NBUCK) bucket_cnt[tid] = 0;

    float acc[8][8];
#pragma unroll
    for (int i = 0; i < 8; i++)
#pragma unroll
        for (int j = 0; j < 8; j++) acc[i][j] = 0.0f;

    // staging-thread geometry (same for all 4 passes)
    const int s_nl  = tid >> 3;               // x: node-local row 0..31 (+32 per pass)
    const int s_c4  = (tid & 7) * 4;          // x: k-col base
    const int s_row = tid >> 5;               // w: k-row 0..7 (+8 per pass)
    const int s_co  = (tid & 31) * 4;         // w: channel base

    float4 xp[4], wp[4];
    // prefetch tile 0
#pragma unroll
    for (int l = 0; l < 4; l++) {
        int nl = s_nl + 32 * l;
        int n  = nodeBase + nl;
        xp[l] = (n < N_NODES) ? *reinterpret_cast<const float4*>(x + (size_t)n * IN_CH + s_c4)
                              : make_float4(0.f, 0.f, 0.f, 0.f);
        wp[l] = *reinterpret_cast<const float4*>(w + (size_t)(s_row + 8 * l) * HID + s_co);
    }

    for (int t = 0; t < 4; t++) {
        if (t) __syncthreads();               // previous compute done before overwrite
#pragma unroll
        for (int l = 0; l < 4; l++) {
            int nl = s_nl + 32 * l;
            // transposed + swizzled x store: W = (c)*128 + nl
            int flip = (((tid & 7) ^ ((nl >> 5) & 3)) << 2);
            float vv[4] = {xp[l].x, xp[l].y, xp[l].z, xp[l].w};
#pragma unroll
            for (int j = 0; j < 4; j++)
                xsw[(((s_c4 + j) << 7) + nl) ^ flip] = vv[j];
            *reinterpret_cast<float4*>(&wsld[s_row + 8 * l][s_co]) = wp[l];
        }
        __syncthreads();

        if (t < 3) {                          // prefetch next tile (overlaps FMA loop)
            int k0n = (t + 1) * BK;
#pragma unroll
            for (int l = 0; l < 4; l++) {
                int nl = s_nl + 32 * l;
                int n  = nodeBase + nl;
                xp[l] = (n < N_NODES) ? *reinterpret_cast<const float4*>(x + (size_t)n * IN_CH + k0n + s_c4)
                                      : make_float4(0.f, 0.f, 0.f, 0.f);
                wp[l] = *reinterpret_cast<const float4*>(w + (size_t)(k0n + s_row + 8 * l) * HID + s_co);
            }
        }

#pragma unroll
        for (int kk = 0; kk < BK; kk++) {
            int fl = ((((kk >> 2) & 7) ^ ((v8 >> 5) & 3)) << 2);
            float4 xlo = *reinterpret_cast<const float4*>(&xsw[((kk << 7) + v8) ^ fl]);
            float4 xhi = *reinterpret_cast<const float4*>(&xsw[((kk << 7) + v8 + 4) ^ fl]);
            float4 wlo = *reinterpret_cast<const float4*>(&wsld[kk][cLo]);
            float4 whi = *reinterpret_cast<const float4*>(&wsld[kk][cHi]);
            float xr[8] = {xlo.x, xlo.y, xlo.z, xlo.w, xhi.x, xhi.y, xhi.z, xhi.w};
            float wr[8] = {wlo.x, wlo.y, wlo.z, wlo.w, whi.x, whi.y, whi.z, whi.w};
#pragma unroll
            for (int i = 0; i < 8; i++)
#pragma unroll
                for (int j = 0; j < 8; j++)
                    acc[i][j] = fmaf(xr[i], wr[j], acc[i][j]);
        }
    }

    // ---- epilogue: bf16 h store + fused scores ----
    const int head_lo = (tid >> 3) & 1;       // ch_lo's head (0 or 1)
    const int head_hi = head_lo + 2;          // ch_hi's head (2 or 3)
    const int cbase   = 4 * (tid & 7);        // channel offset within head
    float4 aslo = *reinterpret_cast<const float4*>(att + head_lo * 64 + cbase);
    float4 adlo = *reinterpret_cast<const float4*>(att + head_lo * 64 + 32 + cbase);
    float4 ashi = *reinterpret_cast<const float4*>(att + head_hi * 64 + cbase);
    float4 adhi = *reinterpret_cast<const float4*>(att + head_hi * 64 + 32 + cbase);

#pragma unroll
    for (int i = 0; i < 8; i++) {
        int n = nodeBase + v8 + i;
        bool ok = (n < N_NODES);
        if (ok) {
            uint2 plo, phi;
            plo.x = (uint)f2bf(acc[i][0]) | ((uint)f2bf(acc[i][1]) << 16);
            plo.y = (uint)f2bf(acc[i][2]) | ((uint)f2bf(acc[i][3]) << 16);
            phi.x = (uint)f2bf(acc[i][4]) | ((uint)f2bf(acc[i][5]) << 16);
            phi.y = (uint)f2bf(acc[i][6]) | ((uint)f2bf(acc[i][7]) << 16);
            *reinterpret_cast<uint2*>(h + (size_t)n * HID + cLo) = plo;
            *reinterpret_cast<uint2*>(h + (size_t)n * HID + cHi) = phi;
        }
        float sl_s = acc[i][0]*aslo.x + acc[i][1]*aslo.y + acc[i][2]*aslo.z + acc[i][3]*aslo.w;
        float sl_d = acc[i][0]*adlo.x + acc[i][1]*adlo.y + acc[i][2]*adlo.z + acc[i][3]*adlo.w;
        float sh_s = acc[i][4]*ashi.x + acc[i][5]*ashi.y + acc[i][6]*ashi.z + acc[i][7]*ashi.w;
        float sh_d = acc[i][4]*adhi.x + acc[i][5]*adhi.y + acc[i][6]*adhi.z + acc[i][7]*adhi.w;
        // reduce over the 8 threads (lane bits 0-2) sharing (node, head)
#pragma unroll
        for (int off = 1; off < 8; off <<= 1) {
            sl_s += __shfl_xor(sl_s, off);
            sl_d += __shfl_xor(sl_d, off);
            sh_s += __shfl_xor(sh_s, off);
            sh_d += __shfl_xor(sh_d, off);
        }
        if ((tid & 7) == 0 && ok) {
            s_src[n * HEADS + head_lo] = sl_s;
            s_dst[n * HEADS + head_lo] = sl_d;
            s_src[n * HEADS + head_hi] = sh_s;
            s_dst[n * HEADS + head_hi] = sh_d;
        }
    }
}

// ---------------- CSR build, stage 1: single-kernel bucket scatter ----------------
// dst kept in 25 registers across both phases (skips the 6.4MB dst re-read).
__global__ __launch_bounds__(256) void k_scatter(const int* __restrict__ ei,
                                                 int* __restrict__ bucket_cnt,
                                                 int* __restrict__ packed) {
    __shared__ int cnt[NBUCK];
    __shared__ int cur[NBUCK];
    int t = threadIdx.x;
    if (t < NBUCK) cnt[t] = 0;
    __syncthreads();
    int base = blockIdx.x * EPB;
    int dreg[25];
#pragma unroll
    for (int j = 0; j < 25; j++) {
        bool ok = (j < 24) || (t < EPB - 24 * 256);   // EPB=6250 -> tail 106
        int e = base + t + j * 256;
        dreg[j] = ok ? ei[N_EDGES + e] : -1;
        if (ok) atomicAdd(&cnt[dreg[j] >> 9], 1);
    }
    __syncthreads();
    if (t < NBUCK) {
        int myBase = atomicAdd(&bucket_cnt[t], cnt[t]);   // device-scope reservation
        cur[t] = t * BSLOT + myBase;
    }
    __syncthreads();
#pragma unroll
    for (int j = 0; j < 25; j++) {
        bool ok = (j < 24) || (t < EPB - 24 * 256);
        if (ok) {
            int e = base + t + j * 256;
            int src = ei[e];
            int d   = dreg[j];
            int pos = atomicAdd(&cur[d >> 9], 1);
            packed[pos] = (src << 9) | (d & (BNODES - 1));   // src<2^17 fits in 26 bits
        }
    }
}

// ---------------- CSR build, stage 2: per-bucket exact CSR + row_start ----------------
// 196 blocks now (was 98 -- half the machine idle). 2 nodes per thread.
__global__ __launch_bounds__(256) void k_b2(const int* __restrict__ packed,
                                            const int* __restrict__ bucket_cnt,
                                            int* __restrict__ csr_src,
                                            int* __restrict__ row_start) {
    __shared__ int cnt[BNODES];
    __shared__ int cur[BNODES];
    __shared__ int sm[256];
    int b = blockIdx.x, t = threadIdx.x;

    // tight output base = exclusive prefix of bucket_cnt over buckets < b
    sm[t] = (t < NBUCK) ? bucket_cnt[t] : 0;
    __syncthreads();
    for (int off = 1; off < 256; off <<= 1) {
        int v = (t >= off) ? sm[t - off] : 0;
        __syncthreads();
        sm[t] += v;
        __syncthreads();
    }
    int myCnt     = bucket_cnt[b];
    int tight_beg = sm[b] - myCnt;
    int beg_pad   = b * BSLOT;
    int end_pad   = beg_pad + myCnt;
    __syncthreads();                       // sm reused below

#pragma unroll
    for (int j = 0; j < 2; j++) cnt[t * 2 + j] = 0;
    __syncthreads();
    for (int e = beg_pad + t; e < end_pad; e += 256)
        atomicAdd(&cnt[packed[e] & (BNODES - 1)], 1);
    __syncthreads();
    int c0 = cnt[t * 2], c1 = cnt[t * 2 + 1];
    int tot = c0 + c1;
    sm[t] = tot;
    __syncthreads();
    for (int off = 1; off < 256; off <<= 1) {
        int v = (t >= off) ? sm[t - off] : 0;
        __syncthreads();
        sm[t] += v;
        __syncthreads();
    }
    int p0 = tight_beg + sm[t] - tot;
    int p1 = p0 + c0;
    cur[t * 2] = p0; cur[t * 2 + 1] = p1;
    int nodeb = b * BNODES + t * 2;
    if (nodeb     <= N_NODES) row_start[nodeb]     = p0;
    if (nodeb + 1 <= N_NODES) row_start[nodeb + 1] = p1;
    __syncthreads();
    for (int e = beg_pad + t; e < end_pad; e += 256) {
        int pk = packed[e];
        int pos = atomicAdd(&cur[pk & (BNODES - 1)], 1);
        csr_src[pos] = pk >> 9;
    }
}

// ---------------- K5: gather aggregation — one wave per node, 4 edges per iter ----------------
// (unchanged: fabric-BW-bound at ~4 TB/s, near its floor)
__global__ __launch_bounds__(256) void k_agg(const int* __restrict__ row_start,
                                             const int* __restrict__ csr_src,
                                             const float* __restrict__ s_src,
                                             const float* __restrict__ s_dst,
                                             const ushort* __restrict__ h,
                                             const float* __restrict__ bias,
                                             float* __restrict__ out) {
    const int n    = blockIdx.x * 4 + (threadIdx.x >> 6);   // 4 nodes per block, 1 wave each
    const int lane = threadIdx.x & 63;
    const int g    = lane >> 4;          // edge sub-group 0..3
    const int q    = lane & 15;          // channel quad: ch = q*8 .. q*8+7
    const int head = q >> 2;             // 32 ch per head / 8 ch per quad

    const float sdh = s_dst[n * HEADS + head];
    const int beg = row_start[n], end = row_start[n + 1];
    const uint4* __restrict__ hrow = reinterpret_cast<const uint4*>(h);   // 16 uint4 per node row

    float acc[8];
#pragma unroll
    for (int k = 0; k < 8; k++) acc[k] = 0.f;
    float sum_w = 0.f;

#pragma unroll 2
    for (int j = beg; j < end; j += 4) {
        int e = j + g;
        bool valid = e < end;
        int src = csr_src[valid ? e : end - 1];          // clamp keeps load safe
        float ss = s_src[src * HEADS + head];            // L2-resident table
        uint4 u = hrow[(size_t)src * (HID / 8) + q];     // 16B = 8 bf16 channels
        float a = ss + sdh;
        a = fmaxf(a, NEG_SLOPE * a);                     // leaky relu
        float wgt = valid ? __expf(a) : 0.f;
        sum_w += wgt;
        uint uv[4] = {u.x, u.y, u.z, u.w};
#pragma unroll
        for (int t = 0; t < 4; t++) {
            acc[2 * t]     = fmaf(wgt, __uint_as_float(uv[t] << 16),        acc[2 * t]);
            acc[2 * t + 1] = fmaf(wgt, __uint_as_float(uv[t] & 0xFFFF0000u), acc[2 * t + 1]);
        }
    }

    // reduce the 4 edge-groups (lanes differing in bits 4,5)
#pragma unroll
    for (int k = 0; k < 8; k++) {
        acc[k] += __shfl_xor(acc[k], 16);
        acc[k] += __shfl_xor(acc[k], 32);
    }
    sum_w += __shfl_xor(sum_w, 16);
    sum_w += __shfl_xor(sum_w, 32);

    if (g == 0) {
        float inv = 1.0f / (sum_w + 1e-16f);
        int ch = q * 8;
        float4 b0 = *reinterpret_cast<const float4*>(bias + ch);
        float4 b1 = *reinterpret_cast<const float4*>(bias + ch + 4);
        float4 o0, o1;
        o0.x = acc[0] * inv + b0.x; o0.y = acc[1] * inv + b0.y;
        o0.z = acc[2] * inv + b0.z; o0.w = acc[3] * inv + b0.w;
        o1.x = acc[4] * inv + b1.x; o1.y = acc[5] * inv + b1.y;
        o1.z = acc[6] * inv + b1.z; o1.w = acc[7] * inv + b1.w;
        *reinterpret_cast<float4*>(out + (size_t)n * HID + ch)     = o0;
        *reinterpret_cast<float4*>(out + (size_t)n * HID + ch + 4) = o1;
    }
}

extern "C" void kernel_launch(void* const* d_in, const int* in_sizes, int n_in,
                              void* d_out, int out_size, void* d_ws, size_t ws_size,
                              hipStream_t stream) {
    const float* x    = (const float*)d_in[0];
    const int*   ei   = (const int*)  d_in[1];
    const float* w    = (const float*)d_in[2];
    const float* att  = (const float*)d_in[3];
    const float* bias = (const float*)d_in[4];
    float* out = (float*)d_out;

    char* p = (char*)d_ws;
    float* s_src    = (float*)p;  p += (size_t)N_NODES * HEADS * 4;   // 1.6 MB
    float* s_dst    = (float*)p;  p += (size_t)N_NODES * HEADS * 4;   // 1.6 MB
    ushort* h       = (ushort*)p; p += (size_t)N_NODES * HID * 2;     // 25.6 MB (16B-aligned)
    int* csr_src    = (int*)p;    p += (size_t)N_EDGES * 4;           // 6.4 MB
    int* packed     = (int*)p;    p += (size_t)NBUCK * BSLOT * 4;     // 7.2 MB (padded buckets)
    int* row_start  = (int*)p;    p += (size_t)(N_NODES + 1) * 4;
    int* bucket_cnt = (int*)p;    p += (size_t)NBUCK * 4;

    k_gemm<<<(N_NODES + BM - 1) / BM, 256, 0, stream>>>(x, w, att, h, s_src, s_dst, bucket_cnt);
    k_scatter<<<NBLK, 256, 0, stream>>>(ei, bucket_cnt, packed);
    k_b2<<<NBUCK, 256, 0, stream>>>(packed, bucket_cnt, csr_src, row_start);
    k_agg<<<N_NODES / 4, 256, 0, stream>>>(row_start, csr_src, s_src, s_dst, h, bias, out);
}

// Round 5
// 284.040 us; speedup vs baseline: 1.1521x; 1.1521x over previous
//
#include <hip/hip_runtime.h>

#define N_NODES 100000
#define N_EDGES 1600000
#define IN_CH   128
#define HEADS   4
#define OUT_CH  32
#define HID     128   // HEADS*OUT_CH
#define NEG_SLOPE 0.2f

#define BNODES  512                       // nodes per bucket (pow2)
#define NBUCK   ((N_NODES + BNODES - 1) / BNODES)   // 196
#define NBLK    256                       // scatter blocks
#define EPB     (N_EDGES / NBLK)          // 6250 edges per block (exact)
#define BSLOT   9216                      // padded slots per bucket (mean 8192, +11 sigma)

typedef unsigned int  uint;
typedef unsigned short ushort;

// bf16 round-to-nearest-even pack
__device__ __forceinline__ ushort f2bf(float f) {
    uint u = __float_as_uint(f);
    return (ushort)((u + 0x7FFFu + ((u >> 16) & 1u)) >> 16);
}

// ---------------- K1: h = x @ W (fp32, bf16 store) + fused attention scores ----------------
// R1 geometry (78us measured; VGPR~88, occupancy-friendly): BM=64, BK=32, 256 thr,
// per thread 4 nodes x 8 channels. Two surgical fixes vs R1:
//  (a) x tile stored TRANSPOSED in a flat swizzled buffer W' = W ^ (((k>>2)&7)<<2)
//      -> transpose scalar stores go 4-way-conflict -> 2-way (free); reads stay
//      16B-aligned b128 broadcasts (conflict-free).  [R2 proved swizzle kills conflicts]
//  (b) channel split cLo=4q / cHi=64+4q -> wsld reads are 16B-lane-stride (2-way max)
//      instead of 32B-stride 4-way.  [epilogue mapping verified in R2]
// NO register prefetch / NO 8x8 acc (that combo caused the R2 occupancy cliff).
#define BM 64
#define BK 32
__global__ __launch_bounds__(256) void k_gemm(const float* __restrict__ x,
                                              const float* __restrict__ w,
                                              const float* __restrict__ att,
                                              ushort* __restrict__ h,
                                              float* __restrict__ s_src,
                                              float* __restrict__ s_dst,
                                              int* __restrict__ bucket_cnt) {
    __shared__ float xsw[BK * BM];            // 8 KB, swizzled, [k][node] transposed
    __shared__ float wsld[BK][HID + 4];       // 16.9 KB

    const int tid = threadIdx.x;
    const int nodeBase = blockIdx.x * BM;
    const int q   = tid & 15;                 // channel quad id
    const int n0  = (tid >> 4) * 4;           // node sub-block base (0..60)
    const int cLo = q * 4;
    const int cHi = 64 + q * 4;

    // zero bucket reservation counters (k_scatter runs after us, stream-ordered)
    if (blockIdx.x == 0 && tid < NBUCK) bucket_cnt[tid] = 0;

    float acc[4][8];
#pragma unroll
    for (int i = 0; i < 4; i++)
#pragma unroll
        for (int j = 0; j < 8; j++) acc[i][j] = 0.0f;

    for (int k0 = 0; k0 < IN_CH; k0 += BK) {
        // ---- stage x (transposed + swizzled) ----
#pragma unroll
        for (int l = 0; l < 2; l++) {
            int idx  = tid + l * 256;
            int node = idx >> 3;              // 0..63
            int c4   = (idx & 7) * 4;         // k-col base
            int n = nodeBase + node;
            float4 v = make_float4(0.f, 0.f, 0.f, 0.f);
            if (n < N_NODES) v = *reinterpret_cast<const float4*>(x + (size_t)n * IN_CH + k0 + c4);
            int flip = (idx & 7) << 2;        // = ((c>>2)&7)<<2 for c = c4..c4+3
            float vv[4] = {v.x, v.y, v.z, v.w};
#pragma unroll
            for (int j = 0; j < 4; j++)
                xsw[(((c4 + j) << 6) + node) ^ flip] = vv[j];
        }
        // ---- stage w (contiguous 16B/lane) ----
#pragma unroll
        for (int l = 0; l < 4; l++) {
            int idx  = tid + l * 256;
            int row  = idx >> 5;              // 0..31
            int col4 = (idx & 31) * 4;
            float4 v = *reinterpret_cast<const float4*>(w + (size_t)(k0 + row) * HID + col4);
            *reinterpret_cast<float4*>(&wsld[row][col4]) = v;
        }
        __syncthreads();

#pragma unroll
        for (int kk = 0; kk < BK; kk++) {
            int flip = ((kk >> 2) & 7) << 2;
            float4 xv  = *reinterpret_cast<const float4*>(&xsw[((kk << 6) + n0) ^ flip]);
            float4 wlo = *reinterpret_cast<const float4*>(&wsld[kk][cLo]);
            float4 whi = *reinterpret_cast<const float4*>(&wsld[kk][cHi]);
            float xr[4] = {xv.x, xv.y, xv.z, xv.w};
            float wr[8] = {wlo.x, wlo.y, wlo.z, wlo.w, whi.x, whi.y, whi.z, whi.w};
#pragma unroll
            for (int i = 0; i < 4; i++)
#pragma unroll
                for (int j = 0; j < 8; j++)
                    acc[i][j] = fmaf(xr[i], wr[j], acc[i][j]);
        }
        __syncthreads();
    }

    // ---- epilogue: bf16 h store + fused scores (mapping verified in R2) ----
    const int head_lo = (tid >> 3) & 1;       // cLo's head (0 or 1)
    const int head_hi = head_lo + 2;          // cHi's head (2 or 3)
    const int cbase   = 4 * (tid & 7);        // channel offset within head
    float4 aslo = *reinterpret_cast<const float4*>(att + head_lo * 64 + cbase);
    float4 adlo = *reinterpret_cast<const float4*>(att + head_lo * 64 + 32 + cbase);
    float4 ashi = *reinterpret_cast<const float4*>(att + head_hi * 64 + cbase);
    float4 adhi = *reinterpret_cast<const float4*>(att + head_hi * 64 + 32 + cbase);

#pragma unroll
    for (int i = 0; i < 4; i++) {
        int n = nodeBase + n0 + i;
        bool ok = (n < N_NODES);
        if (ok) {
            uint2 plo, phi;
            plo.x = (uint)f2bf(acc[i][0]) | ((uint)f2bf(acc[i][1]) << 16);
            plo.y = (uint)f2bf(acc[i][2]) | ((uint)f2bf(acc[i][3]) << 16);
            phi.x = (uint)f2bf(acc[i][4]) | ((uint)f2bf(acc[i][5]) << 16);
            phi.y = (uint)f2bf(acc[i][6]) | ((uint)f2bf(acc[i][7]) << 16);
            *reinterpret_cast<uint2*>(h + (size_t)n * HID + cLo) = plo;
            *reinterpret_cast<uint2*>(h + (size_t)n * HID + cHi) = phi;
        }
        float sl_s = acc[i][0]*aslo.x + acc[i][1]*aslo.y + acc[i][2]*aslo.z + acc[i][3]*aslo.w;
        float sl_d = acc[i][0]*adlo.x + acc[i][1]*adlo.y + acc[i][2]*adlo.z + acc[i][3]*adlo.w;
        float sh_s = acc[i][4]*ashi.x + acc[i][5]*ashi.y + acc[i][6]*ashi.z + acc[i][7]*ashi.w;
        float sh_d = acc[i][4]*adhi.x + acc[i][5]*adhi.y + acc[i][6]*adhi.z + acc[i][7]*adhi.w;
        // reduce over the 8 threads (lane bits 0-2) sharing (node, head)
#pragma unroll
        for (int off = 1; off < 8; off <<= 1) {
            sl_s += __shfl_xor(sl_s, off);
            sl_d += __shfl_xor(sl_d, off);
            sh_s += __shfl_xor(sh_s, off);
            sh_d += __shfl_xor(sh_d, off);
        }
        if ((tid & 7) == 0 && ok) {
            s_src[n * HEADS + head_lo] = sl_s;
            s_dst[n * HEADS + head_lo] = sl_d;
            s_src[n * HEADS + head_hi] = sh_s;
            s_dst[n * HEADS + head_hi] = sh_d;
        }
    }
}

// ---------------- CSR build, stage 1: single-kernel bucket scatter ----------------
// dst kept in 25 registers across both phases (skips the 6.4MB dst re-read).
__global__ __launch_bounds__(256) void k_scatter(const int* __restrict__ ei,
                                                 int* __restrict__ bucket_cnt,
                                                 int* __restrict__ packed) {
    __shared__ int cnt[NBUCK];
    __shared__ int cur[NBUCK];
    int t = threadIdx.x;
    if (t < NBUCK) cnt[t] = 0;
    __syncthreads();
    int base = blockIdx.x * EPB;
    int dreg[25];
#pragma unroll
    for (int j = 0; j < 25; j++) {
        bool ok = (j < 24) || (t < EPB - 24 * 256);   // EPB=6250 -> tail 106
        int e = base + t + j * 256;
        dreg[j] = ok ? ei[N_EDGES + e] : -1;
        if (ok) atomicAdd(&cnt[dreg[j] >> 9], 1);
    }
    __syncthreads();
    if (t < NBUCK) {
        int myBase = atomicAdd(&bucket_cnt[t], cnt[t]);   // device-scope reservation
        cur[t] = t * BSLOT + myBase;
    }
    __syncthreads();
#pragma unroll
    for (int j = 0; j < 25; j++) {
        bool ok = (j < 24) || (t < EPB - 24 * 256);
        if (ok) {
            int e = base + t + j * 256;
            int src = ei[e];
            int d   = dreg[j];
            int pos = atomicAdd(&cur[d >> 9], 1);
            packed[pos] = (src << 9) | (d & (BNODES - 1));   // src<2^17 fits in 26 bits
        }
    }
}

// ---------------- CSR build, stage 2: per-bucket exact CSR + row_start ----------------
__global__ __launch_bounds__(256) void k_b2(const int* __restrict__ packed,
                                            const int* __restrict__ bucket_cnt,
                                            int* __restrict__ csr_src,
                                            int* __restrict__ row_start) {
    __shared__ int cnt[BNODES];
    __shared__ int cur[BNODES];
    __shared__ int sm[256];
    int b = blockIdx.x, t = threadIdx.x;

    // tight output base = exclusive prefix of bucket_cnt over buckets < b
    sm[t] = (t < NBUCK) ? bucket_cnt[t] : 0;
    __syncthreads();
    for (int off = 1; off < 256; off <<= 1) {
        int v = (t >= off) ? sm[t - off] : 0;
        __syncthreads();
        sm[t] += v;
        __syncthreads();
    }
    int myCnt     = bucket_cnt[b];
    int tight_beg = sm[b] - myCnt;
    int beg_pad   = b * BSLOT;
    int end_pad   = beg_pad + myCnt;
    __syncthreads();                       // sm reused below

#pragma unroll
    for (int j = 0; j < 2; j++) cnt[t * 2 + j] = 0;
    __syncthreads();
    for (int e = beg_pad + t; e < end_pad; e += 256)
        atomicAdd(&cnt[packed[e] & (BNODES - 1)], 1);
    __syncthreads();
    int c0 = cnt[t * 2], c1 = cnt[t * 2 + 1];
    int tot = c0 + c1;
    sm[t] = tot;
    __syncthreads();
    for (int off = 1; off < 256; off <<= 1) {
        int v = (t >= off) ? sm[t - off] : 0;
        __syncthreads();
        sm[t] += v;
        __syncthreads();
    }
    int p0 = tight_beg + sm[t] - tot;
    int p1 = p0 + c0;
    cur[t * 2] = p0; cur[t * 2 + 1] = p1;
    int nodeb = b * BNODES + t * 2;
    if (nodeb     <= N_NODES) row_start[nodeb]     = p0;
    if (nodeb + 1 <= N_NODES) row_start[nodeb + 1] = p1;
    __syncthreads();
    for (int e = beg_pad + t; e < end_pad; e += 256) {
        int pk = packed[e];
        int pos = atomicAdd(&cur[pk & (BNODES - 1)], 1);
        csr_src[pos] = pk >> 9;
    }
}

// ---------------- K5: gather aggregation — one wave per node, 4 edges per iter ----------------
// (unchanged: fabric-BW-bound at ~4 TB/s, near its floor)
__global__ __launch_bounds__(256) void k_agg(const int* __restrict__ row_start,
                                             const int* __restrict__ csr_src,
                                             const float* __restrict__ s_src,
                                             const float* __restrict__ s_dst,
                                             const ushort* __restrict__ h,
                                             const float* __restrict__ bias,
                                             float* __restrict__ out) {
    const int n    = blockIdx.x * 4 + (threadIdx.x >> 6);   // 4 nodes per block, 1 wave each
    const int lane = threadIdx.x & 63;
    const int g    = lane >> 4;          // edge sub-group 0..3
    const int q    = lane & 15;          // channel quad: ch = q*8 .. q*8+7
    const int head = q >> 2;             // 32 ch per head / 8 ch per quad

    const float sdh = s_dst[n * HEADS + head];
    const int beg = row_start[n], end = row_start[n + 1];
    const uint4* __restrict__ hrow = reinterpret_cast<const uint4*>(h);   // 16 uint4 per node row

    float acc[8];
#pragma unroll
    for (int k = 0; k < 8; k++) acc[k] = 0.f;
    float sum_w = 0.f;

#pragma unroll 2
    for (int j = beg; j < end; j += 4) {
        int e = j + g;
        bool valid = e < end;
        int src = csr_src[valid ? e : end - 1];          // clamp keeps load safe
        float ss = s_src[src * HEADS + head];            // L2-resident table
        uint4 u = hrow[(size_t)src * (HID / 8) + q];     // 16B = 8 bf16 channels
        float a = ss + sdh;
        a = fmaxf(a, NEG_SLOPE * a);                     // leaky relu
        float wgt = valid ? __expf(a) : 0.f;
        sum_w += wgt;
        uint uv[4] = {u.x, u.y, u.z, u.w};
#pragma unroll
        for (int t = 0; t < 4; t++) {
            acc[2 * t]     = fmaf(wgt, __uint_as_float(uv[t] << 16),        acc[2 * t]);
            acc[2 * t + 1] = fmaf(wgt, __uint_as_float(uv[t] & 0xFFFF0000u), acc[2 * t + 1]);
        }
    }

    // reduce the 4 edge-groups (lanes differing in bits 4,5)
#pragma unroll
    for (int k = 0; k < 8; k++) {
        acc[k] += __shfl_xor(acc[k], 16);
        acc[k] += __shfl_xor(acc[k], 32);
    }
    sum_w += __shfl_xor(sum_w, 16);
    sum_w += __shfl_xor(sum_w, 32);

    if (g == 0) {
        float inv = 1.0f / (sum_w + 1e-16f);
        int ch = q * 8;
        float4 b0 = *reinterpret_cast<const float4*>(bias + ch);
        float4 b1 = *reinterpret_cast<const float4*>(bias + ch + 4);
        float4 o0, o1;
        o0.x = acc[0] * inv + b0.x; o0.y = acc[1] * inv + b0.y;
        o0.z = acc[2] * inv + b0.z; o0.w = acc[3] * inv + b0.w;
        o1.x = acc[4] * inv + b1.x; o1.y = acc[5] * inv + b1.y;
        o1.z = acc[6] * inv + b1.z; o1.w = acc[7] * inv + b1.w;
        *reinterpret_cast<float4*>(out + (size_t)n * HID + ch)     = o0;
        *reinterpret_cast<float4*>(out + (size_t)n * HID + ch + 4) = o1;
    }
}

extern "C" void kernel_launch(void* const* d_in, const int* in_sizes, int n_in,
                              void* d_out, int out_size, void* d_ws, size_t ws_size,
                              hipStream_t stream) {
    const float* x    = (const float*)d_in[0];
    const int*   ei   = (const int*)  d_in[1];
    const float* w    = (const float*)d_in[2];
    const float* att  = (const float*)d_in[3];
    const float* bias = (const float*)d_in[4];
    float* out = (float*)d_out;

    char* p = (char*)d_ws;
    float* s_src    = (float*)p;  p += (size_t)N_NODES * HEADS * 4;   // 1.6 MB
    float* s_dst    = (float*)p;  p += (size_t)N_NODES * HEADS * 4;   // 1.6 MB
    ushort* h       = (ushort*)p; p += (size_t)N_NODES * HID * 2;     // 25.6 MB (16B-aligned)
    int* csr_src    = (int*)p;    p += (size_t)N_EDGES * 4;           // 6.4 MB
    int* packed     = (int*)p;    p += (size_t)NBUCK * BSLOT * 4;     // 7.2 MB (padded buckets)
    int* row_start  = (int*)p;    p += (size_t)(N_NODES + 1) * 4;
    int* bucket_cnt = (int*)p;    p += (size_t)NBUCK * 4;

    k_gemm<<<(N_NODES + BM - 1) / BM, 256, 0, stream>>>(x, w, att, h, s_src, s_dst, bucket_cnt);
    k_scatter<<<NBLK, 256, 0, stream>>>(ei, bucket_cnt, packed);
    k_b2<<<NBUCK, 256, 0, stream>>>(packed, bucket_cnt, csr_src, row_start);
    k_agg<<<N_NODES / 4, 256, 0, stream>>>(row_start, csr_src, s_src, s_dst, h, bias, out);
}